// Round 3
// baseline (453.165 us; speedup 1.0000x reference)
//
#include <hip/hip_runtime.h>
#include <math.h>

#define BATCH 16
#define CH    64
#define HH    128
#define WW    128
#define PLANE (HH*WW)             // 16384
#define OUT0  (BATCH*3*CH*PLANE)  // 50331648
#define SR4    36                 // float4 per staged row (8 pad + 128 + 8 pad)
#define TSROWS 18                 // staged rows per 8-row tile (5 + 8 + 5)
#define PART_OFF 2048             // float offset of per-(b,c,tile) partial sums
#define MB_OFF   90112            // float offset of winner-key buffer (8B aligned)
#define MB_N     786432           // u64 keys: 16 b * 3 fields * 16384 px

// ws layout (floats): [0,1024) M ; [1024,2048) ps ;
// [2048, 83968) partials [b*64+c][16 tiles][5] ; [90112) mb u64[786432] (6.3MB)

// Order-preserving float<->uint encoding (a<b  <=>  enc(a)<enc(b), enc>0 for
// all finite f, so zero-initialized keys lose to every candidate)
__device__ __forceinline__ unsigned enc32(float f) {
    unsigned u = __float_as_uint(f);
    return (u & 0x80000000u) ? ~u : (u | 0x80000000u);
}
__device__ __forceinline__ float dec32(unsigned k) {
    unsigned u = (k & 0x80000000u) ? (k ^ 0x80000000u) : ~k;
    return __uint_as_float(u);
}

// ---------------- Kernel 1: per-(b,c) max -> M, ps; zero key buffer ---------
__global__ __launch_bounds__(256) void k_max(const float* __restrict__ x,
                                             float* __restrict__ ws,
                                             unsigned long long* __restrict__ mb) {
    int bid = blockIdx.x;                    // 0..1023 = b*64+c
    int tid = threadIdx.x;
    // zero this block's slice of the winner-key buffer (768 u64 per block)
    {
        size_t base = (size_t)bid * 768 + tid;
        mb[base] = 0ull; mb[base + 256] = 0ull; mb[base + 512] = 0ull;
    }
    const float4* xp = (const float4*)(x + (size_t)bid * PLANE);
    float m = -INFINITY;
#pragma unroll
    for (int i = 0; i < 16; i++) {
        float4 v = xp[i * 256 + tid];
        m = fmaxf(m, fmaxf(fmaxf(v.x, v.y), fmaxf(v.z, v.w)));
    }
#pragma unroll
    for (int off = 32; off; off >>= 1) m = fmaxf(m, __shfl_xor(m, off, 64));
    __shared__ float sm[4];
    int wid = tid >> 6, lane = tid & 63;
    if (lane == 0) sm[wid] = m;
    __syncthreads();
    if (tid == 0) {
        float mm = fmaxf(fmaxf(sm[0], sm[1]), fmaxf(sm[2], sm[3]));
        float ps = 1.0f / (1.0f + expf(-mm));
        ws[bid] = ps - 0.01f;        // M
        ws[1024 + bid] = ps;         // ps
    }
}

// ---------------- Kernel 2: conv + sums + per-pixel winner keys -------------
// Block = (8-row tile, 16-channel group, b): 1024 blocks, 4/CU co-resident.
__global__ __launch_bounds__(256, 4) void k_conv(
    const float* __restrict__ x,
    const float* __restrict__ w_bbx, const float* __restrict__ w_width,
    const float* __restrict__ w_width_sh, const float* __restrict__ w_height,
    const float* __restrict__ w_height_sh,
    const float* __restrict__ ws, float* __restrict__ wsums,
    unsigned long long* __restrict__ mb) {
    __shared__ float4 xs4[2][TSROWS * SR4];   // 2 x 10368 B = 20.7 KiB
    __shared__ float red[16 * 4 * 5];         // [cc][wave][5] partial sums
    int t = blockIdx.x;                       // row tile 0..15 (8 rows each)
    int g = blockIdx.y;                       // channel group 0..3 (16 ch)
    int b = blockIdx.z;
    int tid = threadIdx.x;
    int r = tid >> 5, q = tid & 31;           // r 0..7 row, q 0..31 col-quad
    int wid = tid >> 6, lane = tid & 63;

    // zero both buffers once (pad columns stay zero; interiors restaged)
    for (int j = tid; j < 2 * TSROWS * SR4; j += 256)
        ((float4*)xs4)[j] = make_float4(0.f, 0.f, 0.f, 0.f);
    __syncthreads();
    int cbase = g * 16;
    // stage first channel into buf 0 (rows t*8-5 .. t*8+12, zeros outside)
    {
        const float* xp = x + (size_t)(b * 64 + cbase) * PLANE;
        for (int j = tid; j < TSROWS * 32; j += 256) {
            int i = j >> 5, c4 = j & 31;
            int gr = t * 8 - 5 + i;
            float4 v = make_float4(0.f, 0.f, 0.f, 0.f);
            if ((unsigned)gr < 128u) v = ((const float4*)xp)[gr * 32 + c4];
            xs4[0][i * SR4 + 2 + c4] = v;
        }
    }
    unsigned long long kW[4], kH[4], kS[4];
#pragma unroll
    for (int j = 0; j < 4; j++) { kW[j] = 0ull; kH[j] = 0ull; kS[j] = 0ull; }

    int cur = 0;
    for (int cc = 0; cc < 16; cc++) {
        __syncthreads();                     // buf[cur] staged & visible
        int c = cbase + cc;
        // prefetch next channel into registers (hidden under compute)
        float4 p0 = make_float4(0.f, 0.f, 0.f, 0.f);
        float4 p1 = make_float4(0.f, 0.f, 0.f, 0.f);
        float4 p2 = make_float4(0.f, 0.f, 0.f, 0.f);
        bool have = (cc + 1 < 16);
        if (have) {
            const float* xp = x + (size_t)(b * 64 + c + 1) * PLANE;
            int i0 = tid >> 5, c4 = tid & 31;
            int g0 = t * 8 - 5 + i0;
            if ((unsigned)g0 < 128u) p0 = ((const float4*)xp)[g0 * 32 + c4];
            int g1 = g0 + 8;
            if ((unsigned)g1 < 128u) p1 = ((const float4*)xp)[g1 * 32 + c4];
            if (tid < 64) {
                int g2 = g0 + 16;
                if ((unsigned)g2 < 128u) p2 = ((const float4*)xp)[g2 * 32 + c4];
            }
        }
        // block-uniform per-channel coefficients -> scalar regs
        float wkc[11], hkc[11];
#pragma unroll
        for (int k = 0; k < 11; k++) {
            wkc[k] = w_width[c * 11 + k];
            hkc[k] = w_height[c * 11 + k];
        }
        float cb = w_bbx[c];
        float cw = 128.0f * w_width_sh[c] * cb;
        float chs = 128.0f * w_height_sh[c] * cb;
        float M = ws[b * 64 + c];

        // vertical 11-tap conv on this thread's 4 columns
        float4 vx;
        float hx = 0.f, hy = 0.f, hz = 0.f, hw = 0.f;
#pragma unroll
        for (int k = 0; k < 11; k++) {
            float4 v = xs4[cur][(r + k) * SR4 + 2 + q];
            if (k == 5) vx = v;
            hx += v.x * hkc[k]; hy += v.y * hkc[k];
            hz += v.z * hkc[k]; hw += v.w * hkc[k];
        }
        // horizontal 11-tap window (padded cols around center row r+5)
        float wbuf[20];
        {
            float4 a0 = xs4[cur][(r + 5) * SR4 + q + 0];
            float4 a1 = xs4[cur][(r + 5) * SR4 + q + 1];
            float4 a3 = xs4[cur][(r + 5) * SR4 + q + 3];
            float4 a4 = xs4[cur][(r + 5) * SR4 + q + 4];
            wbuf[0] = a0.x;  wbuf[1] = a0.y;  wbuf[2] = a0.z;  wbuf[3] = a0.w;
            wbuf[4] = a1.x;  wbuf[5] = a1.y;  wbuf[6] = a1.z;  wbuf[7] = a1.w;
            wbuf[8] = vx.x;  wbuf[9] = vx.y;  wbuf[10] = vx.z; wbuf[11] = vx.w;
            wbuf[12] = a3.x; wbuf[13] = a3.y; wbuf[14] = a3.z; wbuf[15] = a3.w;
            wbuf[16] = a4.x; wbuf[17] = a4.y; wbuf[18] = a4.z; wbuf[19] = a4.w;
        }
        float wo[4];
#pragma unroll
        for (int j = 0; j < 4; j++) {
            float acc = 0.f;
#pragma unroll
            for (int k = 0; k < 11; k++) acc += wbuf[j + 3 + k] * wkc[k];
            wo[j] = acc * cw;
        }
        float ho[4] = {hx * chs, hy * chs, hz * chs, hw * chs};
        float xv[4] = {vx.x, vx.y, vx.z, vx.w};
        float S = 0.f, Sw = 0.f, Sh = 0.f, Scol = 0.f, Srow = 0.f;
#pragma unroll
        for (int j = 0; j < 4; j++) {
            float sx = 1.0f / (1.0f + expf(-xv[j]));
            float sc = (sx > M) ? xv[j] : 0.0f;
            S += sc;
            Sw += wo[j] * sc;
            Sh += ho[j] * sc;
            Scol += (float)(4 * q + j) * sc;
            unsigned long long cand;
            cand = ((unsigned long long)enc32(sc) << 32) | (unsigned)c;
            if (cand > kS[j]) kS[j] = cand;
            cand = ((unsigned long long)enc32(wo[j]) << 32) | (unsigned)c;
            if (cand > kW[j]) kW[j] = cand;
            cand = ((unsigned long long)enc32(ho[j]) << 32) | (unsigned)c;
            if (cand > kH[j]) kH[j] = cand;
        }
        Srow = (float)(t * 8 + r) * S;
        // wave-reduce the 5 sums; lane0 of each wave stores its slot
#pragma unroll
        for (int off = 32; off; off >>= 1) {
            S    += __shfl_xor(S, off, 64);
            Sw   += __shfl_xor(Sw, off, 64);
            Sh   += __shfl_xor(Sh, off, 64);
            Scol += __shfl_xor(Scol, off, 64);
            Srow += __shfl_xor(Srow, off, 64);
        }
        if (lane == 0) {
            float* rr = &red[(cc * 4 + wid) * 5];
            rr[0] = S; rr[1] = Sw; rr[2] = Sh; rr[3] = Scol; rr[4] = Srow;
        }
        if (have) {
            int i0 = tid >> 5, c4 = tid & 31;
            xs4[cur ^ 1][i0 * SR4 + 2 + c4] = p0;
            xs4[cur ^ 1][(i0 + 8) * SR4 + 2 + c4] = p1;
            if (tid < 64) xs4[cur ^ 1][(i0 + 16) * SR4 + 2 + c4] = p2;
        }
        cur ^= 1;
    }
    __syncthreads();
    // fold 4 wave-partials -> per-(b,c,tile) partials (deterministic order)
    if (tid < 80) {
        int cc = tid / 5, j = tid % 5;
        float s = red[(cc * 4 + 0) * 5 + j] + red[(cc * 4 + 1) * 5 + j]
                + red[(cc * 4 + 2) * 5 + j] + red[(cc * 4 + 3) * 5 + j];
        int c = cbase + cc;
        wsums[(((size_t)(b * 64 + c)) * 16 + t) * 5 + j] = s;
    }
    // merge this group's winner keys into the global key buffer
    int gr = t * 8 + r;
    size_t pix = (size_t)gr * 128 + 4 * q;
    size_t i0 = (size_t)(b * 3 + 0) * 16384 + pix;   // score
    size_t i1 = (size_t)(b * 3 + 1) * 16384 + pix;   // w
    size_t i2 = (size_t)(b * 3 + 2) * 16384 + pix;   // h
#pragma unroll
    for (int j = 0; j < 4; j++) {
        atomicMax(&mb[i0 + j], kS[j]);
        atomicMax(&mb[i1 + j], kW[j]);
        atomicMax(&mb[i2 + j], kH[j]);
    }
}

// ---------------- Kernel 3: dense masked write (write-only stream) ----------
__global__ __launch_bounds__(256) void k_scatter(
    const unsigned long long* __restrict__ mb, float* __restrict__ out) {
    int chunk = blockIdx.x;                 // 0..15 (1024-pixel chunk)
    int f = blockIdx.y;                     // 0..2
    int b = blockIdx.z;                     // 0..15
    int tid = threadIdx.x;
    size_t pix = (size_t)chunk * 1024 + tid * 4;
    size_t ki = (size_t)(b * 3 + f) * 16384 + pix;
    float val[4];
    int win[4];
#pragma unroll
    for (int j = 0; j < 4; j++) {
        unsigned long long k = mb[ki + j];
        val[j] = dec32((unsigned)(k >> 32));
        win[j] = (int)(k & 63u);
    }
    float* ob = out + (size_t)(b * 192 + f * 64) * PLANE + pix;
#pragma unroll
    for (int c = 0; c < 64; c++) {
        float4 o;
        o.x = (win[0] == c) ? val[0] : 0.f;
        o.y = (win[1] == c) ? val[1] : 0.f;
        o.z = (win[2] == c) ? val[2] : 0.f;
        o.w = (win[3] == c) ? val[3] : 0.f;
        *(float4*)&ob[(size_t)c * PLANE] = o;
    }
}

// ---------------- Kernel 4: bbox rows (sums 16 tile-partials, fixed order) --
__global__ __launch_bounds__(256) void k_bbox(const float* __restrict__ ws,
                                              float* __restrict__ out) {
    int idx = blockIdx.x * 256 + threadIdx.x;
    if (idx >= 1024) return;
    int b = idx >> 6;
    const float* p = ws + PART_OFF + (size_t)idx * 80;
    float S = 0.f, Sw = 0.f, Sh = 0.f, Scol = 0.f, Srow = 0.f;
#pragma unroll
    for (int t = 0; t < 16; t++) {
        S    += p[t * 5 + 0];
        Sw   += p[t * 5 + 1];
        Sh   += p[t * 5 + 2];
        Scol += p[t * 5 + 3];
        Srow += p[t * 5 + 4];
    }
    float ps = ws[1024 + idx];
    float inv = 1.0f / S;
    float wsv = Sw * inv, hsv = Sh * inv;
    float x1 = Scol * inv - 0.5f * wsv;
    float y1 = Srow * inv - 0.5f * hsv;
    float* o = out + OUT0 + (size_t)idx * 6;
    o[0] = (float)b;
    o[1] = x1;
    o[2] = y1;
    o[3] = x1 + wsv;
    o[4] = y1 + hsv;
    o[5] = ps;
}

extern "C" void kernel_launch(void* const* d_in, const int* in_sizes, int n_in,
                              void* d_out, int out_size, void* d_ws, size_t ws_size,
                              hipStream_t stream) {
    const float* x          = (const float*)d_in[0];
    const float* w_bbx      = (const float*)d_in[1];
    const float* w_width    = (const float*)d_in[2];
    const float* w_width_sh = (const float*)d_in[3];
    const float* w_height   = (const float*)d_in[4];
    const float* w_height_sh= (const float*)d_in[5];
    float* out = (float*)d_out;
    float* ws  = (float*)d_ws;
    unsigned long long* mb = (unsigned long long*)(ws + MB_OFF);

    k_max<<<dim3(1024), dim3(256), 0, stream>>>(x, ws, mb);
    k_conv<<<dim3(16, 4, 16), dim3(256), 0, stream>>>(
        x, w_bbx, w_width, w_width_sh, w_height, w_height_sh,
        ws, ws + PART_OFF, mb);
    k_scatter<<<dim3(16, 3, 16), dim3(256), 0, stream>>>(mb, out);
    k_bbox<<<dim3(4), dim3(256), 0, stream>>>(ws, out);
}

// Round 4
// 400.982 us; speedup vs baseline: 1.1301x; 1.1301x over previous
//
#include <hip/hip_runtime.h>
#include <math.h>

#define BATCH 16
#define CH    64
#define HH    128
#define WW    128
#define PLANE (HH*WW)             // 16384
#define OUT0  (BATCH*3*CH*PLANE)  // 50331648
#define SR4    36                 // float4 per staged row (8 pad + 128 + 8 pad)
#define TSROWS 18                 // staged rows per 8-row tile (5 + 8 + 5)
#define PART_OFF 2048             // float offset of per-(b,c,tile) partial sums
#define MB_OFF   90112            // float offset of winner-key buffers (8B aligned)
#define MB_N     786432           // u64 keys per buffer: 16 b * 3 fields * 16384 px

// ws layout (floats): [0,1024) M ; [1024,2048) ps ;
// [2048, 83968) partials [b*64+c][16 tiles][5] ;
// [90112) mb u64[NG][786432]  (NG = 4 if ws_size permits, else 2)

// Order-preserving float<->uint encoding (a<b  <=>  enc(a)<enc(b); enc>0 for
// all finite f, so a 0 running-key loses to every real candidate)
__device__ __forceinline__ unsigned enc32(float f) {
    unsigned u = __float_as_uint(f);
    return (u & 0x80000000u) ? ~u : (u | 0x80000000u);
}
__device__ __forceinline__ float dec32(unsigned k) {
    unsigned u = (k & 0x80000000u) ? (k ^ 0x80000000u) : ~k;
    return __uint_as_float(u);
}

// ---------------- Kernel 1: per-(b,c) max -> M, ps --------------------------
__global__ __launch_bounds__(256) void k_max(const float* __restrict__ x,
                                             float* __restrict__ ws) {
    int bid = blockIdx.x;                    // 0..1023 = b*64+c
    int tid = threadIdx.x;
    const float4* xp = (const float4*)(x + (size_t)bid * PLANE);
    float m = -INFINITY;
#pragma unroll
    for (int i = 0; i < 16; i++) {
        float4 v = xp[i * 256 + tid];
        m = fmaxf(m, fmaxf(fmaxf(v.x, v.y), fmaxf(v.z, v.w)));
    }
#pragma unroll
    for (int off = 32; off; off >>= 1) m = fmaxf(m, __shfl_xor(m, off, 64));
    __shared__ float sm[4];
    int wid = tid >> 6, lane = tid & 63;
    if (lane == 0) sm[wid] = m;
    __syncthreads();
    if (tid == 0) {
        float mm = fmaxf(fmaxf(sm[0], sm[1]), fmaxf(sm[2], sm[3]));
        float ps = 1.0f / (1.0f + expf(-mm));
        ws[bid] = ps - 0.01f;        // M
        ws[1024 + bid] = ps;         // ps
    }
}

// ---------------- Kernel 2: conv + sums + private per-group winner keys -----
// Block = (8-row tile, CPG-channel group, b). Plain coalesced key stores to
// this group's private buffer: NO atomics, no init needed.
template <int CPG>
__global__ __launch_bounds__(256, 4) void k_conv(
    const float* __restrict__ x,
    const float* __restrict__ w_bbx, const float* __restrict__ w_width,
    const float* __restrict__ w_width_sh, const float* __restrict__ w_height,
    const float* __restrict__ w_height_sh,
    const float* __restrict__ ws, float* __restrict__ wsums,
    unsigned long long* __restrict__ mb) {
    __shared__ float4 xs4[2][TSROWS * SR4];   // 2 x 10368 B = 20.7 KiB
    __shared__ float red[CPG * 4 * 5];        // [cc][wave][5] partial sums
    int t = blockIdx.x;                       // row tile 0..15 (8 rows each)
    int g = blockIdx.y;                       // channel group
    int b = blockIdx.z;
    int tid = threadIdx.x;
    int r = tid >> 5, q = tid & 31;           // r 0..7 row, q 0..31 col-quad
    int wid = tid >> 6, lane = tid & 63;

    // zero both buffers once (pad columns stay zero; interiors restaged)
    for (int j = tid; j < 2 * TSROWS * SR4; j += 256)
        ((float4*)xs4)[j] = make_float4(0.f, 0.f, 0.f, 0.f);
    __syncthreads();
    int cbase = g * CPG;
    // stage first channel into buf 0 (rows t*8-5 .. t*8+12, zeros outside)
    {
        const float* xp = x + (size_t)(b * 64 + cbase) * PLANE;
        for (int j = tid; j < TSROWS * 32; j += 256) {
            int i = j >> 5, c4 = j & 31;
            int gr = t * 8 - 5 + i;
            float4 v = make_float4(0.f, 0.f, 0.f, 0.f);
            if ((unsigned)gr < 128u) v = ((const float4*)xp)[gr * 32 + c4];
            xs4[0][i * SR4 + 2 + c4] = v;
        }
    }
    unsigned long long kW[4], kH[4], kS[4];
#pragma unroll
    for (int j = 0; j < 4; j++) { kW[j] = 0ull; kH[j] = 0ull; kS[j] = 0ull; }

    int cur = 0;
    for (int cc = 0; cc < CPG; cc++) {
        __syncthreads();                     // buf[cur] staged & visible
        int c = cbase + cc;
        // prefetch next channel into registers (hidden under compute)
        float4 p0 = make_float4(0.f, 0.f, 0.f, 0.f);
        float4 p1 = make_float4(0.f, 0.f, 0.f, 0.f);
        float4 p2 = make_float4(0.f, 0.f, 0.f, 0.f);
        bool have = (cc + 1 < CPG);
        if (have) {
            const float* xp = x + (size_t)(b * 64 + c + 1) * PLANE;
            int i0 = tid >> 5, c4 = tid & 31;
            int g0 = t * 8 - 5 + i0;
            if ((unsigned)g0 < 128u) p0 = ((const float4*)xp)[g0 * 32 + c4];
            int g1 = g0 + 8;
            if ((unsigned)g1 < 128u) p1 = ((const float4*)xp)[g1 * 32 + c4];
            if (tid < 64) {
                int g2 = g0 + 16;
                if ((unsigned)g2 < 128u) p2 = ((const float4*)xp)[g2 * 32 + c4];
            }
        }
        // block-uniform per-channel coefficients -> scalar regs
        float wkc[11], hkc[11];
#pragma unroll
        for (int k = 0; k < 11; k++) {
            wkc[k] = w_width[c * 11 + k];
            hkc[k] = w_height[c * 11 + k];
        }
        float cb = w_bbx[c];
        float cw = 128.0f * w_width_sh[c] * cb;
        float chs = 128.0f * w_height_sh[c] * cb;
        float M = ws[b * 64 + c];

        // vertical 11-tap conv on this thread's 4 columns
        float4 vx;
        float hx = 0.f, hy = 0.f, hz = 0.f, hw = 0.f;
#pragma unroll
        for (int k = 0; k < 11; k++) {
            float4 v = xs4[cur][(r + k) * SR4 + 2 + q];
            if (k == 5) vx = v;
            hx += v.x * hkc[k]; hy += v.y * hkc[k];
            hz += v.z * hkc[k]; hw += v.w * hkc[k];
        }
        // horizontal 11-tap window (padded cols around center row r+5)
        float wbuf[20];
        {
            float4 a0 = xs4[cur][(r + 5) * SR4 + q + 0];
            float4 a1 = xs4[cur][(r + 5) * SR4 + q + 1];
            float4 a3 = xs4[cur][(r + 5) * SR4 + q + 3];
            float4 a4 = xs4[cur][(r + 5) * SR4 + q + 4];
            wbuf[0] = a0.x;  wbuf[1] = a0.y;  wbuf[2] = a0.z;  wbuf[3] = a0.w;
            wbuf[4] = a1.x;  wbuf[5] = a1.y;  wbuf[6] = a1.z;  wbuf[7] = a1.w;
            wbuf[8] = vx.x;  wbuf[9] = vx.y;  wbuf[10] = vx.z; wbuf[11] = vx.w;
            wbuf[12] = a3.x; wbuf[13] = a3.y; wbuf[14] = a3.z; wbuf[15] = a3.w;
            wbuf[16] = a4.x; wbuf[17] = a4.y; wbuf[18] = a4.z; wbuf[19] = a4.w;
        }
        float wo[4];
#pragma unroll
        for (int j = 0; j < 4; j++) {
            float acc = 0.f;
#pragma unroll
            for (int k = 0; k < 11; k++) acc += wbuf[j + 3 + k] * wkc[k];
            wo[j] = acc * cw;
        }
        float ho[4] = {hx * chs, hy * chs, hz * chs, hw * chs};
        float xv[4] = {vx.x, vx.y, vx.z, vx.w};
        float S = 0.f, Sw = 0.f, Sh = 0.f, Scol = 0.f, Srow = 0.f;
#pragma unroll
        for (int j = 0; j < 4; j++) {
            float sx = 1.0f / (1.0f + expf(-xv[j]));
            float sc = (sx > M) ? xv[j] : 0.0f;
            S += sc;
            Sw += wo[j] * sc;
            Sh += ho[j] * sc;
            Scol += (float)(4 * q + j) * sc;
            unsigned long long cand;
            cand = ((unsigned long long)enc32(sc) << 32) | (unsigned)c;
            if (cand > kS[j]) kS[j] = cand;
            cand = ((unsigned long long)enc32(wo[j]) << 32) | (unsigned)c;
            if (cand > kW[j]) kW[j] = cand;
            cand = ((unsigned long long)enc32(ho[j]) << 32) | (unsigned)c;
            if (cand > kH[j]) kH[j] = cand;
        }
        Srow = (float)(t * 8 + r) * S;
        // wave-reduce the 5 sums; lane0 of each wave stores its slot
#pragma unroll
        for (int off = 32; off; off >>= 1) {
            S    += __shfl_xor(S, off, 64);
            Sw   += __shfl_xor(Sw, off, 64);
            Sh   += __shfl_xor(Sh, off, 64);
            Scol += __shfl_xor(Scol, off, 64);
            Srow += __shfl_xor(Srow, off, 64);
        }
        if (lane == 0) {
            float* rr = &red[(cc * 4 + wid) * 5];
            rr[0] = S; rr[1] = Sw; rr[2] = Sh; rr[3] = Scol; rr[4] = Srow;
        }
        if (have) {
            int i0 = tid >> 5, c4 = tid & 31;
            xs4[cur ^ 1][i0 * SR4 + 2 + c4] = p0;
            xs4[cur ^ 1][(i0 + 8) * SR4 + 2 + c4] = p1;
            if (tid < 64) xs4[cur ^ 1][(i0 + 16) * SR4 + 2 + c4] = p2;
        }
        cur ^= 1;
    }
    __syncthreads();
    // fold 4 wave-partials -> per-(b,c,tile) partials (deterministic order)
    if (tid < CPG * 5) {
        int cc = tid / 5, j = tid % 5;
        float s = red[(cc * 4 + 0) * 5 + j] + red[(cc * 4 + 1) * 5 + j]
                + red[(cc * 4 + 2) * 5 + j] + red[(cc * 4 + 3) * 5 + j];
        int c = cbase + cc;
        wsums[(((size_t)(b * 64 + c)) * 16 + t) * 5 + j] = s;
    }
    // plain coalesced key stores to this group's PRIVATE buffer (no atomics)
    int gr = t * 8 + r;
    size_t pix = (size_t)gr * 128 + 4 * q;
    unsigned long long* o = mb + (size_t)g * MB_N;
    size_t i0 = (size_t)(b * 3 + 0) * 16384 + pix;   // score
    size_t i1 = (size_t)(b * 3 + 1) * 16384 + pix;   // w
    size_t i2 = (size_t)(b * 3 + 2) * 16384 + pix;   // h
#pragma unroll
    for (int j = 0; j < 4; j++) {
        o[i0 + j] = kS[j];
        o[i1 + j] = kW[j];
        o[i2 + j] = kH[j];
    }
}

// ---------------- Kernel 3: merge NG key buffers + dense masked write -------
template <int NG>
__global__ __launch_bounds__(256) void k_scatter(
    const unsigned long long* __restrict__ mb, float* __restrict__ out) {
    int chunk = blockIdx.x;                 // 0..15 (1024-pixel chunk)
    int f = blockIdx.y;                     // 0..2
    int b = blockIdx.z;                     // 0..15
    int tid = threadIdx.x;
    size_t pix = (size_t)chunk * 1024 + tid * 4;
    size_t ki = (size_t)(b * 3 + f) * 16384 + pix;
    float val[4];
    int win[4];
#pragma unroll
    for (int j = 0; j < 4; j++) {
        unsigned long long k = 0ull;
#pragma unroll
        for (int g2 = 0; g2 < NG; g2++) {
            unsigned long long kg = mb[(size_t)g2 * MB_N + ki + j];
            if (kg > k) k = kg;
        }
        val[j] = dec32((unsigned)(k >> 32));
        win[j] = (int)(k & 63u);
    }
    float* ob = out + (size_t)(b * 192 + f * 64) * PLANE + pix;
#pragma unroll
    for (int c = 0; c < 64; c++) {
        float4 o;
        o.x = (win[0] == c) ? val[0] : 0.f;
        o.y = (win[1] == c) ? val[1] : 0.f;
        o.z = (win[2] == c) ? val[2] : 0.f;
        o.w = (win[3] == c) ? val[3] : 0.f;
        *(float4*)&ob[(size_t)c * PLANE] = o;
    }
}

// ---------------- Kernel 4: bbox rows (sums 16 tile-partials, fixed order) --
__global__ __launch_bounds__(256) void k_bbox(const float* __restrict__ ws,
                                              float* __restrict__ out) {
    int idx = blockIdx.x * 256 + threadIdx.x;
    if (idx >= 1024) return;
    int b = idx >> 6;
    const float* p = ws + PART_OFF + (size_t)idx * 80;
    float S = 0.f, Sw = 0.f, Sh = 0.f, Scol = 0.f, Srow = 0.f;
#pragma unroll
    for (int t = 0; t < 16; t++) {
        S    += p[t * 5 + 0];
        Sw   += p[t * 5 + 1];
        Sh   += p[t * 5 + 2];
        Scol += p[t * 5 + 3];
        Srow += p[t * 5 + 4];
    }
    float ps = ws[1024 + idx];
    float inv = 1.0f / S;
    float wsv = Sw * inv, hsv = Sh * inv;
    float x1 = Scol * inv - 0.5f * wsv;
    float y1 = Srow * inv - 0.5f * hsv;
    float* o = out + OUT0 + (size_t)idx * 6;
    o[0] = (float)b;
    o[1] = x1;
    o[2] = y1;
    o[3] = x1 + wsv;
    o[4] = y1 + hsv;
    o[5] = ps;
}

extern "C" void kernel_launch(void* const* d_in, const int* in_sizes, int n_in,
                              void* d_out, int out_size, void* d_ws, size_t ws_size,
                              hipStream_t stream) {
    const float* x          = (const float*)d_in[0];
    const float* w_bbx      = (const float*)d_in[1];
    const float* w_width    = (const float*)d_in[2];
    const float* w_width_sh = (const float*)d_in[3];
    const float* w_height   = (const float*)d_in[4];
    const float* w_height_sh= (const float*)d_in[5];
    float* out = (float*)d_out;
    float* ws  = (float*)d_ws;
    unsigned long long* mb = (unsigned long long*)(ws + MB_OFF);

    // 4 private key buffers need 24.4 MiB of ws; fall back to 2 (proven
    // footprint from an earlier round) if the workspace is smaller.
    size_t need4 = (size_t)MB_OFF * 4 + 4ull * MB_N * 8ull;

    k_max<<<dim3(1024), dim3(256), 0, stream>>>(x, ws);
    if (ws_size >= need4) {
        k_conv<16><<<dim3(16, 4, 16), dim3(256), 0, stream>>>(
            x, w_bbx, w_width, w_width_sh, w_height, w_height_sh,
            ws, ws + PART_OFF, mb);
        k_scatter<4><<<dim3(16, 3, 16), dim3(256), 0, stream>>>(mb, out);
    } else {
        k_conv<32><<<dim3(16, 2, 16), dim3(256), 0, stream>>>(
            x, w_bbx, w_width, w_width_sh, w_height, w_height_sh,
            ws, ws + PART_OFF, mb);
        k_scatter<2><<<dim3(16, 3, 16), dim3(256), 0, stream>>>(mb, out);
    }
    k_bbox<<<dim3(4), dim3(256), 0, stream>>>(ws, out);
}

// Round 5
// 348.284 us; speedup vs baseline: 1.3011x; 1.1513x over previous
//
#include <hip/hip_runtime.h>
#include <math.h>

#define BATCH 16
#define CH    64
#define HH    128
#define WW    128
#define PLANE (HH*WW)             // 16384
#define OUT0  (BATCH*3*CH*PLANE)  // 50331648
#define SR4    36                 // float4 per staged row (8 pad + 128 + 8 pad)
#define TSROWS 18                 // staged rows per 8-row tile (5 + 8 + 5)
#define PART_OFF 2048             // float offset of per-(b,c,tile) partial sums
#define MB_OFF   90112            // float offset of winner-key buffers (8B aligned)
#define MB_N     786432           // u64 keys per buffer: 16 b * 3 fields * 16384 px

// ws layout (floats): [0,1024) M ; [1024,2048) ps ;
// [2048, 83968) partials [b*64+c][16 tiles][5] ;
// [90112) mb u64[NG][786432]  (NG = 4 if ws_size permits, else 2)

// Order-preserving float<->uint encoding (a<b  <=>  enc(a)<enc(b); enc>0 for
// all finite f, so a 0 running-key loses to every real candidate)
__device__ __forceinline__ unsigned enc32(float f) {
    unsigned u = __float_as_uint(f);
    return (u & 0x80000000u) ? ~u : (u | 0x80000000u);
}
__device__ __forceinline__ float dec32(unsigned k) {
    unsigned u = (k & 0x80000000u) ? (k ^ 0x80000000u) : ~k;
    return __uint_as_float(u);
}

// ---------------- Kernel 1: per-(b,c) max -> M, ps --------------------------
__global__ __launch_bounds__(256) void k_max(const float* __restrict__ x,
                                             float* __restrict__ ws) {
    int bid = blockIdx.x;                    // 0..1023 = b*64+c
    int tid = threadIdx.x;
    const float4* xp = (const float4*)(x + (size_t)bid * PLANE);
    float m = -INFINITY;
#pragma unroll
    for (int i = 0; i < 16; i++) {
        float4 v = xp[i * 256 + tid];
        m = fmaxf(m, fmaxf(fmaxf(v.x, v.y), fmaxf(v.z, v.w)));
    }
#pragma unroll
    for (int off = 32; off; off >>= 1) m = fmaxf(m, __shfl_xor(m, off, 64));
    __shared__ float sm[4];
    int wid = tid >> 6, lane = tid & 63;
    if (lane == 0) sm[wid] = m;
    __syncthreads();
    if (tid == 0) {
        float mm = fmaxf(fmaxf(sm[0], sm[1]), fmaxf(sm[2], sm[3]));
        float ps = 1.0f / (1.0f + expf(-mm));
        ws[bid] = ps - 0.01f;        // M
        ws[1024 + bid] = ps;         // ps
    }
}

// ---------------- Kernel 2: conv + sums + private per-group winner keys -----
// Block = (8-row tile, CPG-channel group, b). Plain coalesced key stores to
// this group's private buffer: NO atomics, no init needed.
// NOTE: no min-waves clamp — VGPR=64 forced ~300 MB of scratch spill traffic
// (round 3/4 post-mortem). Register pressure here genuinely needs ~100-160.
template <int CPG>
__global__ __launch_bounds__(256) void k_conv(
    const float* __restrict__ x,
    const float* __restrict__ w_bbx, const float* __restrict__ w_width,
    const float* __restrict__ w_width_sh, const float* __restrict__ w_height,
    const float* __restrict__ w_height_sh,
    const float* __restrict__ ws, float* __restrict__ wsums,
    unsigned long long* __restrict__ mb) {
    __shared__ float4 xs4[2][TSROWS * SR4];   // 2 x 10368 B = 20.7 KiB
    __shared__ float red[CPG * 4 * 5];        // [cc][wave][5] partial sums
    int t = blockIdx.x;                       // row tile 0..15 (8 rows each)
    int g = blockIdx.y;                       // channel group
    int b = blockIdx.z;
    int tid = threadIdx.x;
    int r = tid >> 5, q = tid & 31;           // r 0..7 row, q 0..31 col-quad
    int wid = tid >> 6, lane = tid & 63;

    // zero both buffers once (pad columns stay zero; interiors restaged)
    for (int j = tid; j < 2 * TSROWS * SR4; j += 256)
        ((float4*)xs4)[j] = make_float4(0.f, 0.f, 0.f, 0.f);
    __syncthreads();
    int cbase = g * CPG;
    // stage first channel into buf 0 (rows t*8-5 .. t*8+12, zeros outside)
    {
        const float* xp = x + (size_t)(b * 64 + cbase) * PLANE;
        for (int j = tid; j < TSROWS * 32; j += 256) {
            int i = j >> 5, c4 = j & 31;
            int gr = t * 8 - 5 + i;
            float4 v = make_float4(0.f, 0.f, 0.f, 0.f);
            if ((unsigned)gr < 128u) v = ((const float4*)xp)[gr * 32 + c4];
            xs4[0][i * SR4 + 2 + c4] = v;
        }
    }
    unsigned long long kW[4], kH[4], kS[4];
#pragma unroll
    for (int j = 0; j < 4; j++) { kW[j] = 0ull; kH[j] = 0ull; kS[j] = 0ull; }

    int cur = 0;
    for (int cc = 0; cc < CPG; cc++) {
        __syncthreads();                     // buf[cur] staged & visible
        int c = cbase + cc;
        // prefetch next channel into registers (hidden under compute)
        float4 p0 = make_float4(0.f, 0.f, 0.f, 0.f);
        float4 p1 = make_float4(0.f, 0.f, 0.f, 0.f);
        float4 p2 = make_float4(0.f, 0.f, 0.f, 0.f);
        bool have = (cc + 1 < CPG);
        if (have) {
            const float* xp = x + (size_t)(b * 64 + c + 1) * PLANE;
            int i0 = tid >> 5, c4 = tid & 31;
            int g0 = t * 8 - 5 + i0;
            if ((unsigned)g0 < 128u) p0 = ((const float4*)xp)[g0 * 32 + c4];
            int g1 = g0 + 8;
            if ((unsigned)g1 < 128u) p1 = ((const float4*)xp)[g1 * 32 + c4];
            if (tid < 64) {
                int g2 = g0 + 16;
                if ((unsigned)g2 < 128u) p2 = ((const float4*)xp)[g2 * 32 + c4];
            }
        }
        // block-uniform per-channel coefficients -> scalar regs
        float wkc[11], hkc[11];
#pragma unroll
        for (int k = 0; k < 11; k++) {
            wkc[k] = w_width[c * 11 + k];
            hkc[k] = w_height[c * 11 + k];
        }
        float cb = w_bbx[c];
        float cw = 128.0f * w_width_sh[c] * cb;
        float chs = 128.0f * w_height_sh[c] * cb;
        float M = ws[b * 64 + c];

        // vertical 11-tap conv on this thread's 4 columns
        float4 vx;
        float hx = 0.f, hy = 0.f, hz = 0.f, hw = 0.f;
#pragma unroll
        for (int k = 0; k < 11; k++) {
            float4 v = xs4[cur][(r + k) * SR4 + 2 + q];
            if (k == 5) vx = v;
            hx += v.x * hkc[k]; hy += v.y * hkc[k];
            hz += v.z * hkc[k]; hw += v.w * hkc[k];
        }
        // horizontal 11-tap window (padded cols around center row r+5)
        float wbuf[20];
        {
            float4 a0 = xs4[cur][(r + 5) * SR4 + q + 0];
            float4 a1 = xs4[cur][(r + 5) * SR4 + q + 1];
            float4 a3 = xs4[cur][(r + 5) * SR4 + q + 3];
            float4 a4 = xs4[cur][(r + 5) * SR4 + q + 4];
            wbuf[0] = a0.x;  wbuf[1] = a0.y;  wbuf[2] = a0.z;  wbuf[3] = a0.w;
            wbuf[4] = a1.x;  wbuf[5] = a1.y;  wbuf[6] = a1.z;  wbuf[7] = a1.w;
            wbuf[8] = vx.x;  wbuf[9] = vx.y;  wbuf[10] = vx.z; wbuf[11] = vx.w;
            wbuf[12] = a3.x; wbuf[13] = a3.y; wbuf[14] = a3.z; wbuf[15] = a3.w;
            wbuf[16] = a4.x; wbuf[17] = a4.y; wbuf[18] = a4.z; wbuf[19] = a4.w;
        }
        float wo[4];
#pragma unroll
        for (int j = 0; j < 4; j++) {
            float acc = 0.f;
#pragma unroll
            for (int k = 0; k < 11; k++) acc += wbuf[j + 3 + k] * wkc[k];
            wo[j] = acc * cw;
        }
        float ho[4] = {hx * chs, hy * chs, hz * chs, hw * chs};
        float xv[4] = {vx.x, vx.y, vx.z, vx.w};
        float S = 0.f, Sw = 0.f, Sh = 0.f, Scol = 0.f, Srow = 0.f;
#pragma unroll
        for (int j = 0; j < 4; j++) {
            float sx = 1.0f / (1.0f + expf(-xv[j]));
            float sc = (sx > M) ? xv[j] : 0.0f;
            S += sc;
            Sw += wo[j] * sc;
            Sh += ho[j] * sc;
            Scol += (float)(4 * q + j) * sc;
            unsigned long long cand;
            cand = ((unsigned long long)enc32(sc) << 32) | (unsigned)c;
            if (cand > kS[j]) kS[j] = cand;
            cand = ((unsigned long long)enc32(wo[j]) << 32) | (unsigned)c;
            if (cand > kW[j]) kW[j] = cand;
            cand = ((unsigned long long)enc32(ho[j]) << 32) | (unsigned)c;
            if (cand > kH[j]) kH[j] = cand;
        }
        Srow = (float)(t * 8 + r) * S;
        // wave-reduce the 5 sums; lane0 of each wave stores its slot
#pragma unroll
        for (int off = 32; off; off >>= 1) {
            S    += __shfl_xor(S, off, 64);
            Sw   += __shfl_xor(Sw, off, 64);
            Sh   += __shfl_xor(Sh, off, 64);
            Scol += __shfl_xor(Scol, off, 64);
            Srow += __shfl_xor(Srow, off, 64);
        }
        if (lane == 0) {
            float* rr = &red[(cc * 4 + wid) * 5];
            rr[0] = S; rr[1] = Sw; rr[2] = Sh; rr[3] = Scol; rr[4] = Srow;
        }
        if (have) {
            int i0 = tid >> 5, c4 = tid & 31;
            xs4[cur ^ 1][i0 * SR4 + 2 + c4] = p0;
            xs4[cur ^ 1][(i0 + 8) * SR4 + 2 + c4] = p1;
            if (tid < 64) xs4[cur ^ 1][(i0 + 16) * SR4 + 2 + c4] = p2;
        }
        cur ^= 1;
    }
    __syncthreads();
    // fold 4 wave-partials -> per-(b,c,tile) partials (deterministic order)
    if (tid < CPG * 5) {
        int cc = tid / 5, j = tid % 5;
        float s = red[(cc * 4 + 0) * 5 + j] + red[(cc * 4 + 1) * 5 + j]
                + red[(cc * 4 + 2) * 5 + j] + red[(cc * 4 + 3) * 5 + j];
        int c = cbase + cc;
        wsums[(((size_t)(b * 64 + c)) * 16 + t) * 5 + j] = s;
    }
    // plain coalesced key stores to this group's PRIVATE buffer (no atomics)
    int gr = t * 8 + r;
    size_t pix = (size_t)gr * 128 + 4 * q;
    unsigned long long* o = mb + (size_t)g * MB_N;
    size_t i0 = (size_t)(b * 3 + 0) * 16384 + pix;   // score
    size_t i1 = (size_t)(b * 3 + 1) * 16384 + pix;   // w
    size_t i2 = (size_t)(b * 3 + 2) * 16384 + pix;   // h
#pragma unroll
    for (int j = 0; j < 4; j++) {
        o[i0 + j] = kS[j];
        o[i1 + j] = kW[j];
        o[i2 + j] = kH[j];
    }
}

// ---------------- Kernel 3: merge NG key buffers + dense masked write -------
template <int NG>
__global__ __launch_bounds__(256) void k_scatter(
    const unsigned long long* __restrict__ mb, float* __restrict__ out) {
    int chunk = blockIdx.x;                 // 0..15 (1024-pixel chunk)
    int f = blockIdx.y;                     // 0..2
    int b = blockIdx.z;                     // 0..15
    int tid = threadIdx.x;
    size_t pix = (size_t)chunk * 1024 + tid * 4;
    size_t ki = (size_t)(b * 3 + f) * 16384 + pix;
    float val[4];
    int win[4];
#pragma unroll
    for (int j = 0; j < 4; j++) {
        unsigned long long k = 0ull;
#pragma unroll
        for (int g2 = 0; g2 < NG; g2++) {
            unsigned long long kg = mb[(size_t)g2 * MB_N + ki + j];
            if (kg > k) k = kg;
        }
        val[j] = dec32((unsigned)(k >> 32));
        win[j] = (int)(k & 63u);
    }
    float* ob = out + (size_t)(b * 192 + f * 64) * PLANE + pix;
#pragma unroll
    for (int c = 0; c < 64; c++) {
        float4 o;
        o.x = (win[0] == c) ? val[0] : 0.f;
        o.y = (win[1] == c) ? val[1] : 0.f;
        o.z = (win[2] == c) ? val[2] : 0.f;
        o.w = (win[3] == c) ? val[3] : 0.f;
        *(float4*)&ob[(size_t)c * PLANE] = o;
    }
}

// ---------------- Kernel 4: bbox rows (sums 16 tile-partials, fixed order) --
__global__ __launch_bounds__(256) void k_bbox(const float* __restrict__ ws,
                                              float* __restrict__ out) {
    int idx = blockIdx.x * 256 + threadIdx.x;
    if (idx >= 1024) return;
    int b = idx >> 6;
    const float* p = ws + PART_OFF + (size_t)idx * 80;
    float S = 0.f, Sw = 0.f, Sh = 0.f, Scol = 0.f, Srow = 0.f;
#pragma unroll
    for (int t = 0; t < 16; t++) {
        S    += p[t * 5 + 0];
        Sw   += p[t * 5 + 1];
        Sh   += p[t * 5 + 2];
        Scol += p[t * 5 + 3];
        Srow += p[t * 5 + 4];
    }
    float ps = ws[1024 + idx];
    float inv = 1.0f / S;
    float wsv = Sw * inv, hsv = Sh * inv;
    float x1 = Scol * inv - 0.5f * wsv;
    float y1 = Srow * inv - 0.5f * hsv;
    float* o = out + OUT0 + (size_t)idx * 6;
    o[0] = (float)b;
    o[1] = x1;
    o[2] = y1;
    o[3] = x1 + wsv;
    o[4] = y1 + hsv;
    o[5] = ps;
}

extern "C" void kernel_launch(void* const* d_in, const int* in_sizes, int n_in,
                              void* d_out, int out_size, void* d_ws, size_t ws_size,
                              hipStream_t stream) {
    const float* x          = (const float*)d_in[0];
    const float* w_bbx      = (const float*)d_in[1];
    const float* w_width    = (const float*)d_in[2];
    const float* w_width_sh = (const float*)d_in[3];
    const float* w_height   = (const float*)d_in[4];
    const float* w_height_sh= (const float*)d_in[5];
    float* out = (float*)d_out;
    float* ws  = (float*)d_ws;
    unsigned long long* mb = (unsigned long long*)(ws + MB_OFF);

    // 4 private key buffers need 24.4 MiB of ws; fall back to 2 (proven
    // footprint from an earlier round) if the workspace is smaller.
    size_t need4 = (size_t)MB_OFF * 4 + 4ull * MB_N * 8ull;

    k_max<<<dim3(1024), dim3(256), 0, stream>>>(x, ws);
    if (ws_size >= need4) {
        k_conv<16><<<dim3(16, 4, 16), dim3(256), 0, stream>>>(
            x, w_bbx, w_width, w_width_sh, w_height, w_height_sh,
            ws, ws + PART_OFF, mb);
        k_scatter<4><<<dim3(16, 3, 16), dim3(256), 0, stream>>>(mb, out);
    } else {
        k_conv<32><<<dim3(16, 2, 16), dim3(256), 0, stream>>>(
            x, w_bbx, w_width, w_width_sh, w_height, w_height_sh,
            ws, ws + PART_OFF, mb);
        k_scatter<2><<<dim3(16, 3, 16), dim3(256), 0, stream>>>(mb, out);
    }
    k_bbox<<<dim3(4), dim3(256), 0, stream>>>(ws, out);
}

// Round 6
// 338.037 us; speedup vs baseline: 1.3406x; 1.0303x over previous
//
#include <hip/hip_runtime.h>
#include <math.h>

#define BATCH 16
#define CH    64
#define HH    128
#define WW    128
#define PLANE (HH*WW)             // 16384
#define OUT0  (BATCH*3*CH*PLANE)  // 50331648
#define SR4    36                 // float4 per staged row (8 pad + 128 + 8 pad)
#define TSROWS 18                 // staged rows per 8-row tile  (5 + 8 + 5)
#define T16R   26                 // staged rows per 16-row tile (5 + 16 + 5)
#define PART_OFF 2048             // float offset of per-(b,c,tile) partial sums
#define MB_OFF   90112            // float offset of winner-key buffers (8B aligned)
#define MB_N     786432           // u64 keys per buffer: 16 b * 3 fields * 16384 px

typedef float f4v __attribute__((ext_vector_type(4)));

// ws layout (floats): [0,1024) M ; [1024,2048) ps ;
// [2048,...) partials [b*64+c][NT tiles][5] (NT=8 main / 16 fallback) ;
// [90112) mb u64[NG][786432]  (NG = 4 if ws_size permits, else 2)

// Order-preserving float<->uint encoding (a<b  <=>  enc(a)<enc(b); enc>0 for
// all finite f, so a 0 running-key loses to every real candidate)
__device__ __forceinline__ unsigned enc32(float f) {
    unsigned u = __float_as_uint(f);
    return (u & 0x80000000u) ? ~u : (u | 0x80000000u);
}
__device__ __forceinline__ float dec32(unsigned k) {
    unsigned u = (k & 0x80000000u) ? (k ^ 0x80000000u) : ~k;
    return __uint_as_float(u);
}

// ---------------- Kernel 1: per-(b,c) max -> M, ps --------------------------
__global__ __launch_bounds__(256) void k_max(const float* __restrict__ x,
                                             float* __restrict__ ws) {
    int bid = blockIdx.x;                    // 0..1023 = b*64+c
    int tid = threadIdx.x;
    const float4* xp = (const float4*)(x + (size_t)bid * PLANE);
    float m = -INFINITY;
#pragma unroll
    for (int i = 0; i < 16; i++) {
        float4 v = xp[i * 256 + tid];
        m = fmaxf(m, fmaxf(fmaxf(v.x, v.y), fmaxf(v.z, v.w)));
    }
#pragma unroll
    for (int off = 32; off; off >>= 1) m = fmaxf(m, __shfl_xor(m, off, 64));
    __shared__ float sm[4];
    int wid = tid >> 6, lane = tid & 63;
    if (lane == 0) sm[wid] = m;
    __syncthreads();
    if (tid == 0) {
        float mm = fmaxf(fmaxf(sm[0], sm[1]), fmaxf(sm[2], sm[3]));
        float ps = 1.0f / (1.0f + expf(-mm));
        ws[bid] = ps - 0.01f;        // M
        ws[1024 + bid] = ps;         // ps
    }
}

// ---------------- Kernel 2 (main): 16-row tiles, paired rows, XCD swizzle ---
// 1D grid of 512: bid -> xcd=bid&7, k=(bid>>3)&7, t=bid>>6; gb=xcd*8+k.
// All 8 row-tiles of one (g,b) share bid%8 -> same XCD -> halo rows L2-hit.
// Thread owns rows {2r,2r+1} x cols {4q..4q+3} (8 px): vertical taps shared.
// Occupancy grid-capped at 2 blocks/CU -> VGPRs free (launch_bounds min=1).
__global__ __launch_bounds__(256, 1) void k_conv16(
    const float* __restrict__ x,
    const float* __restrict__ w_bbx, const float* __restrict__ w_width,
    const float* __restrict__ w_width_sh, const float* __restrict__ w_height,
    const float* __restrict__ w_height_sh,
    const float* __restrict__ ws, float* __restrict__ wsums,
    unsigned long long* __restrict__ mb) {
    __shared__ float4 xs4[2][T16R * SR4];     // 2 x 14976 B = 29.25 KiB
    __shared__ float red[16 * 4 * 5];         // [cc][wave][5]
    int bid = blockIdx.x;
    int xcd = bid & 7, kk = (bid >> 3) & 7, t = bid >> 6;   // t 0..7
    int gb = xcd * 8 + kk;
    int g = gb & 3, b = gb >> 2;
    int tid = threadIdx.x;
    int r = tid >> 5, q = tid & 31;           // r 0..7 row-pair, q 0..31 quad
    int wid = tid >> 6, lane = tid & 63;

    for (int j = tid; j < 2 * T16R * SR4; j += 256)
        ((float4*)xs4)[j] = make_float4(0.f, 0.f, 0.f, 0.f);
    __syncthreads();
    int cbase = g * 16;
    {   // stage first channel into buf 0 (rows t*16-5 .. t*16+20)
        const float* xp = x + (size_t)(b * 64 + cbase) * PLANE;
        for (int j = tid; j < T16R * 32; j += 256) {
            int i = j >> 5, c4 = j & 31;
            int gr = t * 16 - 5 + i;
            float4 v = make_float4(0.f, 0.f, 0.f, 0.f);
            if ((unsigned)gr < 128u) v = ((const float4*)xp)[gr * 32 + c4];
            xs4[0][i * SR4 + 2 + c4] = v;
        }
    }
    unsigned long long kS[2][4], kW[2][4], kH[2][4];
#pragma unroll
    for (int rr = 0; rr < 2; rr++)
#pragma unroll
        for (int j = 0; j < 4; j++) { kS[rr][j] = 0; kW[rr][j] = 0; kH[rr][j] = 0; }

    int cur = 0;
    for (int cc = 0; cc < 16; cc++) {
        __syncthreads();                     // buf[cur] staged & visible
        int c = cbase + cc;
        // prefetch next channel (26*32=832 f4 over 256 thr: 4 slices)
        float4 p0 = make_float4(0,0,0,0), p1 = p0, p2 = p0, p3 = p0;
        bool have = (cc + 1 < 16);
        int i0 = tid >> 5, c4 = tid & 31;
        if (have) {
            const float* xp = x + (size_t)(b * 64 + c + 1) * PLANE;
            int gr0 = t * 16 - 5 + i0;
            if ((unsigned)gr0 < 128u) p0 = ((const float4*)xp)[gr0 * 32 + c4];
            int gr1 = gr0 + 8;
            if ((unsigned)gr1 < 128u) p1 = ((const float4*)xp)[gr1 * 32 + c4];
            int gr2 = gr0 + 16;
            if ((unsigned)gr2 < 128u) p2 = ((const float4*)xp)[gr2 * 32 + c4];
            if (tid < 64) {
                int gr3 = gr0 + 24;
                if ((unsigned)gr3 < 128u) p3 = ((const float4*)xp)[gr3 * 32 + c4];
            }
        }
        float wkc[11], hkc[11];
#pragma unroll
        for (int k = 0; k < 11; k++) {
            wkc[k] = w_width[c * 11 + k];
            hkc[k] = w_height[c * 11 + k];
        }
        float cb = w_bbx[c];
        float cw = 128.0f * w_width_sh[c] * cb;
        float chs = 128.0f * w_height_sh[c] * cb;
        float M = ws[b * 64 + c];

        // vertical 11-tap conv for both rows, rolling over 12 staged rows
        float a0x=0,a0y=0,a0z=0,a0w=0, a1x=0,a1y=0,a1z=0,a1w=0;
        float4 vx0, vx1;
#pragma unroll
        for (int k = 0; k < 12; k++) {
            float4 v = xs4[cur][(2 * r + k) * SR4 + 2 + q];
            if (k == 5) vx0 = v;
            if (k == 6) vx1 = v;
            if (k < 11) {
                float h = hkc[k];
                a0x += v.x*h; a0y += v.y*h; a0z += v.z*h; a0w += v.w*h;
            }
            if (k >= 1) {
                float h = hkc[k-1];
                a1x += v.x*h; a1y += v.y*h; a1z += v.z*h; a1w += v.w*h;
            }
        }
        float ho[2][4] = {{a0x*chs, a0y*chs, a0z*chs, a0w*chs},
                          {a1x*chs, a1y*chs, a1z*chs, a1w*chs}};
        float S = 0.f, Sw = 0.f, Sh = 0.f, Scol = 0.f, Srow = 0.f;
#pragma unroll
        for (int rr = 0; rr < 2; rr++) {
            float4 vc = (rr == 0) ? vx0 : vx1;
            int srow = (2 * r + 5 + rr) * SR4 + q;
            float4 b0 = xs4[cur][srow + 0];
            float4 b1 = xs4[cur][srow + 1];
            float4 b3 = xs4[cur][srow + 3];
            float4 b4 = xs4[cur][srow + 4];
            float wbuf[20] = {b0.x,b0.y,b0.z,b0.w, b1.x,b1.y,b1.z,b1.w,
                              vc.x,vc.y,vc.z,vc.w, b3.x,b3.y,b3.z,b3.w,
                              b4.x,b4.y,b4.z,b4.w};
            float xv[4] = {vc.x, vc.y, vc.z, vc.w};
            float s4 = 0.f;
#pragma unroll
            for (int j = 0; j < 4; j++) {
                float acc = 0.f;
#pragma unroll
                for (int k = 0; k < 11; k++) acc += wbuf[j + 3 + k] * wkc[k];
                float wo = acc * cw;
                float sx = 1.0f / (1.0f + expf(-xv[j]));
                float sc = (sx > M) ? xv[j] : 0.0f;
                s4 += sc;
                Sw += wo * sc;
                Sh += ho[rr][j] * sc;
                Scol += (float)(4 * q + j) * sc;
                unsigned long long cand;
                cand = ((unsigned long long)enc32(sc) << 32) | (unsigned)c;
                if (cand > kS[rr][j]) kS[rr][j] = cand;
                cand = ((unsigned long long)enc32(wo) << 32) | (unsigned)c;
                if (cand > kW[rr][j]) kW[rr][j] = cand;
                cand = ((unsigned long long)enc32(ho[rr][j]) << 32) | (unsigned)c;
                if (cand > kH[rr][j]) kH[rr][j] = cand;
            }
            S += s4;
            Srow += (float)(t * 16 + 2 * r + rr) * s4;
        }
        // wave-reduce the 5 sums
#pragma unroll
        for (int off = 32; off; off >>= 1) {
            S    += __shfl_xor(S, off, 64);
            Sw   += __shfl_xor(Sw, off, 64);
            Sh   += __shfl_xor(Sh, off, 64);
            Scol += __shfl_xor(Scol, off, 64);
            Srow += __shfl_xor(Srow, off, 64);
        }
        if (lane == 0) {
            float* rr2 = &red[(cc * 4 + wid) * 5];
            rr2[0] = S; rr2[1] = Sw; rr2[2] = Sh; rr2[3] = Scol; rr2[4] = Srow;
        }
        if (have) {
            xs4[cur ^ 1][i0 * SR4 + 2 + c4] = p0;
            xs4[cur ^ 1][(i0 + 8) * SR4 + 2 + c4] = p1;
            xs4[cur ^ 1][(i0 + 16) * SR4 + 2 + c4] = p2;
            if (tid < 64) xs4[cur ^ 1][(i0 + 24) * SR4 + 2 + c4] = p3;
        }
        cur ^= 1;
    }
    __syncthreads();
    // fold 4 wave-partials -> per-(b,c,tile) partials (deterministic order)
    if (tid < 80) {
        int cc = tid / 5, j = tid % 5;
        float s = red[(cc * 4 + 0) * 5 + j] + red[(cc * 4 + 1) * 5 + j]
                + red[(cc * 4 + 2) * 5 + j] + red[(cc * 4 + 3) * 5 + j];
        int c = cbase + cc;
        wsums[(((size_t)(b * 64 + c)) * 8 + t) * 5 + j] = s;
    }
    // plain coalesced key stores to this group's PRIVATE buffer
    int y0 = t * 16 + 2 * r;
    size_t pix = (size_t)y0 * 128 + 4 * q;
    unsigned long long* o = mb + (size_t)g * MB_N;
    size_t i0s = (size_t)(b * 3 + 0) * 16384 + pix;
    size_t i1s = (size_t)(b * 3 + 1) * 16384 + pix;
    size_t i2s = (size_t)(b * 3 + 2) * 16384 + pix;
#pragma unroll
    for (int rr = 0; rr < 2; rr++)
#pragma unroll
        for (int j = 0; j < 4; j++) {
            o[i0s + rr * 128 + j] = kS[rr][j];
            o[i1s + rr * 128 + j] = kW[rr][j];
            o[i2s + rr * 128 + j] = kH[rr][j];
        }
}

// ---------------- Kernel 2 (fallback, proven round-5 shape): 8-row tiles ----
template <int CPG>
__global__ __launch_bounds__(256) void k_conv(
    const float* __restrict__ x,
    const float* __restrict__ w_bbx, const float* __restrict__ w_width,
    const float* __restrict__ w_width_sh, const float* __restrict__ w_height,
    const float* __restrict__ w_height_sh,
    const float* __restrict__ ws, float* __restrict__ wsums,
    unsigned long long* __restrict__ mb) {
    __shared__ float4 xs4[2][TSROWS * SR4];
    __shared__ float red[CPG * 4 * 5];
    int t = blockIdx.x, g = blockIdx.y, b = blockIdx.z;
    int tid = threadIdx.x;
    int r = tid >> 5, q = tid & 31;
    int wid = tid >> 6, lane = tid & 63;
    for (int j = tid; j < 2 * TSROWS * SR4; j += 256)
        ((float4*)xs4)[j] = make_float4(0.f, 0.f, 0.f, 0.f);
    __syncthreads();
    int cbase = g * CPG;
    {
        const float* xp = x + (size_t)(b * 64 + cbase) * PLANE;
        for (int j = tid; j < TSROWS * 32; j += 256) {
            int i = j >> 5, c4 = j & 31;
            int gr = t * 8 - 5 + i;
            float4 v = make_float4(0.f, 0.f, 0.f, 0.f);
            if ((unsigned)gr < 128u) v = ((const float4*)xp)[gr * 32 + c4];
            xs4[0][i * SR4 + 2 + c4] = v;
        }
    }
    unsigned long long kW[4], kH[4], kS[4];
#pragma unroll
    for (int j = 0; j < 4; j++) { kW[j] = 0ull; kH[j] = 0ull; kS[j] = 0ull; }
    int cur = 0;
    for (int cc = 0; cc < CPG; cc++) {
        __syncthreads();
        int c = cbase + cc;
        float4 p0 = make_float4(0,0,0,0), p1 = p0, p2 = p0;
        bool have = (cc + 1 < CPG);
        if (have) {
            const float* xp = x + (size_t)(b * 64 + c + 1) * PLANE;
            int i0 = tid >> 5, c4 = tid & 31;
            int g0 = t * 8 - 5 + i0;
            if ((unsigned)g0 < 128u) p0 = ((const float4*)xp)[g0 * 32 + c4];
            int g1 = g0 + 8;
            if ((unsigned)g1 < 128u) p1 = ((const float4*)xp)[g1 * 32 + c4];
            if (tid < 64) {
                int g2 = g0 + 16;
                if ((unsigned)g2 < 128u) p2 = ((const float4*)xp)[g2 * 32 + c4];
            }
        }
        float wkc[11], hkc[11];
#pragma unroll
        for (int k = 0; k < 11; k++) {
            wkc[k] = w_width[c * 11 + k];
            hkc[k] = w_height[c * 11 + k];
        }
        float cb = w_bbx[c];
        float cw = 128.0f * w_width_sh[c] * cb;
        float chs = 128.0f * w_height_sh[c] * cb;
        float M = ws[b * 64 + c];
        float4 vx;
        float hx = 0.f, hy = 0.f, hz = 0.f, hw = 0.f;
#pragma unroll
        for (int k = 0; k < 11; k++) {
            float4 v = xs4[cur][(r + k) * SR4 + 2 + q];
            if (k == 5) vx = v;
            hx += v.x * hkc[k]; hy += v.y * hkc[k];
            hz += v.z * hkc[k]; hw += v.w * hkc[k];
        }
        float wbuf[20];
        {
            float4 a0 = xs4[cur][(r + 5) * SR4 + q + 0];
            float4 a1 = xs4[cur][(r + 5) * SR4 + q + 1];
            float4 a3 = xs4[cur][(r + 5) * SR4 + q + 3];
            float4 a4 = xs4[cur][(r + 5) * SR4 + q + 4];
            wbuf[0]=a0.x; wbuf[1]=a0.y; wbuf[2]=a0.z; wbuf[3]=a0.w;
            wbuf[4]=a1.x; wbuf[5]=a1.y; wbuf[6]=a1.z; wbuf[7]=a1.w;
            wbuf[8]=vx.x; wbuf[9]=vx.y; wbuf[10]=vx.z; wbuf[11]=vx.w;
            wbuf[12]=a3.x; wbuf[13]=a3.y; wbuf[14]=a3.z; wbuf[15]=a3.w;
            wbuf[16]=a4.x; wbuf[17]=a4.y; wbuf[18]=a4.z; wbuf[19]=a4.w;
        }
        float wo[4];
#pragma unroll
        for (int j = 0; j < 4; j++) {
            float acc = 0.f;
#pragma unroll
            for (int k = 0; k < 11; k++) acc += wbuf[j + 3 + k] * wkc[k];
            wo[j] = acc * cw;
        }
        float ho[4] = {hx * chs, hy * chs, hz * chs, hw * chs};
        float xv[4] = {vx.x, vx.y, vx.z, vx.w};
        float S = 0.f, Sw = 0.f, Sh = 0.f, Scol = 0.f, Srow = 0.f;
#pragma unroll
        for (int j = 0; j < 4; j++) {
            float sx = 1.0f / (1.0f + expf(-xv[j]));
            float sc = (sx > M) ? xv[j] : 0.0f;
            S += sc; Sw += wo[j] * sc; Sh += ho[j] * sc;
            Scol += (float)(4 * q + j) * sc;
            unsigned long long cand;
            cand = ((unsigned long long)enc32(sc) << 32) | (unsigned)c;
            if (cand > kS[j]) kS[j] = cand;
            cand = ((unsigned long long)enc32(wo[j]) << 32) | (unsigned)c;
            if (cand > kW[j]) kW[j] = cand;
            cand = ((unsigned long long)enc32(ho[j]) << 32) | (unsigned)c;
            if (cand > kH[j]) kH[j] = cand;
        }
        Srow = (float)(t * 8 + r) * S;
#pragma unroll
        for (int off = 32; off; off >>= 1) {
            S    += __shfl_xor(S, off, 64);
            Sw   += __shfl_xor(Sw, off, 64);
            Sh   += __shfl_xor(Sh, off, 64);
            Scol += __shfl_xor(Scol, off, 64);
            Srow += __shfl_xor(Srow, off, 64);
        }
        if (lane == 0) {
            float* rr = &red[(cc * 4 + wid) * 5];
            rr[0] = S; rr[1] = Sw; rr[2] = Sh; rr[3] = Scol; rr[4] = Srow;
        }
        if (have) {
            int i0 = tid >> 5, c4 = tid & 31;
            xs4[cur ^ 1][i0 * SR4 + 2 + c4] = p0;
            xs4[cur ^ 1][(i0 + 8) * SR4 + 2 + c4] = p1;
            if (tid < 64) xs4[cur ^ 1][(i0 + 16) * SR4 + 2 + c4] = p2;
        }
        cur ^= 1;
    }
    __syncthreads();
    if (tid < CPG * 5) {
        int cc = tid / 5, j = tid % 5;
        float s = red[(cc * 4 + 0) * 5 + j] + red[(cc * 4 + 1) * 5 + j]
                + red[(cc * 4 + 2) * 5 + j] + red[(cc * 4 + 3) * 5 + j];
        int c = cbase + cc;
        wsums[(((size_t)(b * 64 + c)) * 16 + t) * 5 + j] = s;
    }
    int gr = t * 8 + r;
    size_t pix = (size_t)gr * 128 + 4 * q;
    unsigned long long* o = mb + (size_t)g * MB_N;
    size_t i0 = (size_t)(b * 3 + 0) * 16384 + pix;
    size_t i1 = (size_t)(b * 3 + 1) * 16384 + pix;
    size_t i2 = (size_t)(b * 3 + 2) * 16384 + pix;
#pragma unroll
    for (int j = 0; j < 4; j++) {
        o[i0 + j] = kS[j];
        o[i1 + j] = kW[j];
        o[i2 + j] = kH[j];
    }
}

// ---------------- Kernel 3: merge NG key buffers + dense masked write -------
template <int NG>
__global__ __launch_bounds__(256) void k_scatter(
    const unsigned long long* __restrict__ mb, float* __restrict__ out) {
    int chunk = blockIdx.x;                 // 0..15 (1024-pixel chunk)
    int f = blockIdx.y;                     // 0..2
    int b = blockIdx.z;                     // 0..15
    int tid = threadIdx.x;
    size_t pix = (size_t)chunk * 1024 + tid * 4;
    size_t ki = (size_t)(b * 3 + f) * 16384 + pix;
    float val[4];
    int win[4];
#pragma unroll
    for (int j = 0; j < 4; j++) {
        unsigned long long k = 0ull;
#pragma unroll
        for (int g2 = 0; g2 < NG; g2++) {
            unsigned long long kg = mb[(size_t)g2 * MB_N + ki + j];
            if (kg > k) k = kg;
        }
        val[j] = dec32((unsigned)(k >> 32));
        win[j] = (int)(k & 63u);
    }
    float* ob = out + (size_t)(b * 192 + f * 64) * PLANE + pix;
#pragma unroll
    for (int c = 0; c < 64; c++) {
        f4v o;
        o.x = (win[0] == c) ? val[0] : 0.f;
        o.y = (win[1] == c) ? val[1] : 0.f;
        o.z = (win[2] == c) ? val[2] : 0.f;
        o.w = (win[3] == c) ? val[3] : 0.f;
        __builtin_nontemporal_store(o, (f4v*)&ob[(size_t)c * PLANE]);
    }
}

// ---------------- Kernel 4: bbox rows (sums NT tile-partials, fixed order) --
template <int NT>
__global__ __launch_bounds__(256) void k_bbox(const float* __restrict__ ws,
                                              float* __restrict__ out) {
    int idx = blockIdx.x * 256 + threadIdx.x;
    if (idx >= 1024) return;
    int b = idx >> 6;
    const float* p = ws + PART_OFF + (size_t)idx * (NT * 5);
    float S = 0.f, Sw = 0.f, Sh = 0.f, Scol = 0.f, Srow = 0.f;
#pragma unroll
    for (int t = 0; t < NT; t++) {
        S    += p[t * 5 + 0];
        Sw   += p[t * 5 + 1];
        Sh   += p[t * 5 + 2];
        Scol += p[t * 5 + 3];
        Srow += p[t * 5 + 4];
    }
    float ps = ws[1024 + idx];
    float inv = 1.0f / S;
    float wsv = Sw * inv, hsv = Sh * inv;
    float x1 = Scol * inv - 0.5f * wsv;
    float y1 = Srow * inv - 0.5f * hsv;
    float* o = out + OUT0 + (size_t)idx * 6;
    o[0] = (float)b;
    o[1] = x1;
    o[2] = y1;
    o[3] = x1 + wsv;
    o[4] = y1 + hsv;
    o[5] = ps;
}

extern "C" void kernel_launch(void* const* d_in, const int* in_sizes, int n_in,
                              void* d_out, int out_size, void* d_ws, size_t ws_size,
                              hipStream_t stream) {
    const float* x          = (const float*)d_in[0];
    const float* w_bbx      = (const float*)d_in[1];
    const float* w_width    = (const float*)d_in[2];
    const float* w_width_sh = (const float*)d_in[3];
    const float* w_height   = (const float*)d_in[4];
    const float* w_height_sh= (const float*)d_in[5];
    float* out = (float*)d_out;
    float* ws  = (float*)d_ws;
    unsigned long long* mb = (unsigned long long*)(ws + MB_OFF);

    size_t need4 = (size_t)MB_OFF * 4 + 4ull * MB_N * 8ull;   // 25.5 MB

    k_max<<<dim3(1024), dim3(256), 0, stream>>>(x, ws);
    if (ws_size >= need4) {
        k_conv16<<<dim3(512), dim3(256), 0, stream>>>(
            x, w_bbx, w_width, w_width_sh, w_height, w_height_sh,
            ws, ws + PART_OFF, mb);
        k_scatter<4><<<dim3(16, 3, 16), dim3(256), 0, stream>>>(mb, out);
        k_bbox<8><<<dim3(4), dim3(256), 0, stream>>>(ws, out);
    } else {
        k_conv<32><<<dim3(16, 2, 16), dim3(256), 0, stream>>>(
            x, w_bbx, w_width, w_width_sh, w_height, w_height_sh,
            ws, ws + PART_OFF, mb);
        k_scatter<2><<<dim3(16, 3, 16), dim3(256), 0, stream>>>(mb, out);
        k_bbox<16><<<dim3(4), dim3(256), 0, stream>>>(ws, out);
    }
}